// Round 14
// baseline (18917.984 us; speedup 1.0000x reference)
//
#include <hip/hip_runtime.h>
#include <cstddef>
#include <cstdint>

#define Hd 51
#define Td 2048
#define NBb 2       // batches per block
#define NTH 768     // 12 waves: 4xL0, 4xL1, 4xL2 (one of each per SIMD)
#define NBLK 512    // 2 blocks per CU -> cross-block phase overlap

typedef _Float16 f16x8 __attribute__((ext_vector_type(8)));
typedef _Float16 f16x4 __attribute__((ext_vector_type(4)));
typedef float    f32x4 __attribute__((ext_vector_type(4)));

// LDS layout identical to R13 (64 KB; 2 blocks x 64KB = 128KB <= 160KB/CU):
//  buf0/1/2: double-buffered h panels, chunk-transposed (16B chunks @256B)
//  PRE: preact exchange [l][c] blocks of 64 slots x 16B (f32x4 {i,f,g,o})
//  XP : whole-sequence x panel, f16, xp[t][slot], slot = f*4+n
#define RB0   128
#define RB12  256
#define BASE0 0
#define BASE1 4096
#define BASE2 12288
#define PRE   20480
#define XP    32768
#define LDSB  65536

#define LOG2E  1.44269504f
#define LOG2E2 2.88539008f

__device__ __forceinline__ int vaddr(int base, int rowB, int db, int n, int off) {
    return base + db * (16 * rowB) + ((off >> 4) << 8) + (n << 4) + (off & 15);
}

// preact slot: bijective (m4 = elem&15, n) <-> slot
__device__ __forceinline__ int pslot(int m4, int n) {
    return ((m4 ^ n) & 15) | (n << 4);
}

__device__ __forceinline__ float fast_rcp(float x) { return __builtin_amdgcn_rcpf(x); }
__device__ __forceinline__ float exp2_fast(float x) {
#if __has_builtin(__builtin_amdgcn_exp2f)
    return __builtin_amdgcn_exp2f(x);
#else
    return exp2f(x);
#endif
}

// preactivations arrive PRE-SCALED: a' = a*log2e (i,f,o) or a*2*log2e (g)
__device__ __forceinline__ float sigm2(float ap)  { return fast_rcp(1.f + exp2_fast(-ap)); }
__device__ __forceinline__ float tanh2(float ap)  { return fmaf(2.f, fast_rcp(1.f + exp2_fast(-ap)), -1.f); }
__device__ __forceinline__ float tanh_c(float x) {   // x in true units
    float e = exp2_fast(-LOG2E2 * fabsf(x));
    float t = (1.f - e) * fast_rcp(1.f + e);
    return copysignf(t, x);
}

__global__ __launch_bounds__(NTH, 6)   // 6 waves/SIMD -> VGPR <= 85 (2 blocks/CU)
void lstm3_mfma(const float* __restrict__ g_input, const float* __restrict__ g_time,
                const float* __restrict__ Wih0, const float* __restrict__ Whh0,
                const float* __restrict__ bih0, const float* __restrict__ bhh0,
                const float* __restrict__ Wih1, const float* __restrict__ Whh1,
                const float* __restrict__ bih1, const float* __restrict__ bhh1,
                const float* __restrict__ Wih2, const float* __restrict__ Whh2,
                const float* __restrict__ bih2, const float* __restrict__ bhh2,
                const float* __restrict__ Wlin, const float* __restrict__ blin,
                float* __restrict__ g_out)
{
    __shared__ __align__(16) unsigned char lds[LDSB];

    const int tid  = threadIdx.x;
    const int lane = tid & 63;
    const int w    = tid >> 6;       // wave 0..11
    const int g    = w >> 2;         // layer group: 0=L0, 1=L1, 2=L2
    const int c    = w & 3;          // element-chunk (16 gate-elements / tile set)
    const int ncol = lane & 15;      // batch col (B) / A-row-in-tile
    const int kg   = lane >> 4;      // k-group 0..3
    const int b0   = blockIdx.x * NBb;

    // ---- zero LDS (h buffers must be 0) ----
    for (int i = tid * 4; i < LDSB; i += NTH * 4) *(uint32_t*)(lds + i) = 0u;
    __syncthreads();

    // one-slots (bias column of B) in BOTH double buffers; x(t=0)
    if (tid < 32) {
        int db = tid >> 4, n = tid & 15;
        *(unsigned short*)(lds + vaddr(BASE0, RB0,  db, n,  54 * 2)) = 0x3C00; // f16 1.0
        *(unsigned short*)(lds + vaddr(BASE1, RB12, db, n, 112 * 2)) = 0x3C00;
        *(unsigned short*)(lds + vaddr(BASE2, RB12, db, n, 112 * 2)) = 0x3C00;
    } else if (tid >= 64 && tid < 68) {
        int i = tid - 64; int n = i & 1, f = i >> 1;
        const float* src = f ? g_time : g_input;
        float v = src[(size_t)(b0 + n) * Td];
        *(_Float16*)(lds + vaddr(BASE0, RB0, 0, n, (52 + f) * 2)) = (_Float16)v;
    }

    // ---- preload ALL x into XP panel (coalesced float4, one-time) ----
    // chunks: 2 feat x 2 batch x 512 float4 = 2048
    for (int i = tid; i < 2048; i += NTH) {
        const int f  = i >> 10;
        const int rm = i & 1023;
        const int n  = rm >> 9;
        const int t4 = rm & 511;
        const float* src = f ? g_time : g_input;
        float4 v = *(const float4*)&src[(size_t)(b0 + n) * Td + 4 * t4];
        const int slot = f * 4 + n;
        #pragma unroll
        for (int j = 0; j < 4; ++j)
            *(_Float16*)(lds + XP + ((((4 * t4 + j) << 3) + slot) << 1)) = (_Float16)((&v.x)[j]);
    }

    // ---- load weight A-fragments (f16, log2e-prescaled) ----
    // A-frag lane map (16x16x32): row = 16*tile + (lane&15), k = 32*s + 8*(lane>>4) + e
    // wave owns tiles {c, c+4, c+8, c+12}: gate gs rows = 64*gs + er, er = 16c + ncol
    const int er = 16 * c + ncol;
    const bool rvalid = (er < Hd);
    f16x8 AF[16];   // g0: [0..7] = 4 gates x 2 ksteps; g1/g2: [0..15] = 4 gates x 4 ksteps

    if (g == 0) {
        #pragma unroll
        for (int gs = 0; gs < 4; ++gs) {
            const int sr = gs * Hd + er;
            const float S = (gs == 2) ? LOG2E2 : LOG2E;   // g-gate: tanh(a)=2sig(2a)-1
            #pragma unroll
            for (int s = 0; s < 2; ++s)
                #pragma unroll
                for (int e = 0; e < 8; ++e) {
                    const int kk = 32 * s + 8 * kg + e;
                    float v = 0.f;
                    if (rvalid) {
                        if (kk < 51)                   v = Whh0[sr * 51 + kk];
                        else if (kk == 52 || kk == 53) v = Wih0[sr * 2 + (kk - 52)];
                        else if (kk == 54)             v = bih0[sr] + bhh0[sr];
                    }
                    AF[gs * 2 + s][e] = (_Float16)(v * S);
                }
        }
    } else {
        const float* Wih = (g == 1) ? Wih1 : Wih2;   // prev-layer h (k 0..50)
        const float* Whh = (g == 1) ? Whh1 : Whh2;   // own h (k 56..106)
        const float* bihp = (g == 1) ? bih1 : bih2;
        const float* bhhp = (g == 1) ? bhh1 : bhh2;
        #pragma unroll
        for (int gs = 0; gs < 4; ++gs) {
            const int sr = gs * Hd + er;
            const float S = (gs == 2) ? LOG2E2 : LOG2E;
            #pragma unroll
            for (int s = 0; s < 4; ++s)
                #pragma unroll
                for (int e = 0; e < 8; ++e) {
                    const int kk = 32 * s + 8 * kg + e;
                    float v = 0.f;
                    float sc = S;
                    if (rvalid) {
                        if (kk < 51)                   v = Wih[sr * 51 + kk];
                        else if (kk >= 56 && kk < 107) v = Whh[sr * 51 + (kk - 56)];
                        else if (kk == 112)            v = bihp[sr] + bhhp[sr];
                    } else if (g == 2 && gs == 0 && (er == 52 || er == 53)) {
                        const int hr = er - 52;        // head rows: LINEAR, unscaled
                        sc = 1.f;
                        if (kk >= 56 && kk < 107)      v = Wlin[hr * 51 + (kk - 56)];
                        else if (kk == 112)            v = blin[hr];
                    }
                    AF[gs * 4 + s][e] = (_Float16)(v * sc);
                }
        }
    }

    // ---- hoisted MFMA-phase addresses ----
    const f32x4 Z = {0.f, 0.f, 0.f, 0.f};
    const int PAR0 = 16 * RB0;    // db stride buf0
    const int PAR12 = 16 * RB12;  // db stride buf1/2
    int rd0a = vaddr(BASE0, RB0, 0, ncol, 16 * kg);
    int rd0b = vaddr(BASE0, RB0, 0, ncol, 64 + 16 * kg);
    int rd12[4];
    {
        const int baseg = (g == 2) ? BASE2 : BASE1;
        #pragma unroll
        for (int s = 0; s < 4; ++s) rd12[s] = vaddr(baseg, RB12, 0, ncol, 64 * s + 16 * kg);
    }
    // preact write addrs (one per C row r); valid iff ncol<NBb && e0+r<51
    const int e0 = 16 * c + 4 * kg;
    int pw[4];
    bool pwok[4];
    #pragma unroll
    for (int r = 0; r < 4; ++r) {
        pw[r] = PRE + ((g * 4 + c) << 10) + (pslot(4 * kg + r, ncol & 3) << 4);
        pwok[r] = (ncol < NBb) && (e0 + r < Hd);
    }

    // ---- update-thread decode: u = w*26 + lane (lane<26), 306 cells ----
    const int u = w * 26 + lane;
    const bool uok = (lane < 26) && (u < 3 * Hd * NBb);
    int ul = 0, prd = 0, wh1 = 0, wh2 = 0, str1 = 0;
    bool has2 = false;
    if (uok) {
        ul = u / (Hd * NBb);             // layer 0..2 (may diverge in boundary waves)
        const int rr = u - ul * (Hd * NBb);
        const int ue = rr >> 1;          // element 0..50
        const int un = rr & 1;           // batch 0..1
        prd = PRE + ((ul * 4 + (ue >> 4)) << 10) + (pslot(ue & 15, un) << 4);
        if (ul == 0) {
            wh1 = vaddr(BASE0, RB0,  0, un, 2 * ue);       str1 = PAR0;
            wh2 = vaddr(BASE1, RB12, 0, un, 2 * ue);       has2 = true;
        } else if (ul == 1) {
            wh1 = vaddr(BASE1, RB12, 0, un, 112 + 2 * ue); str1 = PAR12;
            wh2 = vaddr(BASE2, RB12, 0, un, 2 * ue);       has2 = true;
        } else {
            wh1 = vaddr(BASE2, RB12, 0, un, 112 + 2 * ue); str1 = PAR12;
        }
    }
    float ucs = 0.f;   // persistent c-state of this thread's cell

    // loop-carried B operands: lanes ncol>=NBb stay ZERO forever (masked reads)
    f16x8 zf;
    #pragma unroll
    for (int e = 0; e < 8; ++e) zf[e] = (_Float16)0.f;
    f16x8 B0 = zf, B1 = zf;                        // g0
    f16x8 Bv0 = zf, Bv1 = zf, Bv2 = zf, Bv3 = zf;  // g1/g2

    __syncthreads();

    // layer skew: iter n computes L0@t=n, L1@t=n-1, L2@t=n-2, head@t=n-3
    for (int n = 0; n <= Td + 2; ++n) {
        const int rb = n & 1, wb = rb ^ 1;
        const int rP0 = rb * PAR0, rP12 = rb * PAR12;

        // ================= MFMA phase =================
        if (g == 0) {
            const bool dopf = (w == 0 && lane < 8 && (n + 1) < Td);
            _Float16 pfh = (_Float16)0.f;
            const int nb = lane & 3, f = lane >> 2;
            if (dopf)   // x from LDS panel: ~30cyc, never stalls the barrier
                pfh = *(const _Float16*)(lds + XP + ((((n + 1) << 3) + lane) << 1));
            if (n < Td) {
                if (ncol < NBb) {   // masked: only real batch columns hit LDS
                    B0 = *(const f16x8*)(lds + rd0a + rP0);
                    B1 = *(const f16x8*)(lds + rd0b + rP0);
                }
                f32x4 a_i = Z, a_f = Z, a_g = Z, a_o = Z;
                __builtin_amdgcn_s_setprio(1);
                a_i = __builtin_amdgcn_mfma_f32_16x16x32_f16(AF[0], B0, a_i, 0, 0, 0);
                a_i = __builtin_amdgcn_mfma_f32_16x16x32_f16(AF[1], B1, a_i, 0, 0, 0);
                a_f = __builtin_amdgcn_mfma_f32_16x16x32_f16(AF[2], B0, a_f, 0, 0, 0);
                a_f = __builtin_amdgcn_mfma_f32_16x16x32_f16(AF[3], B1, a_f, 0, 0, 0);
                a_g = __builtin_amdgcn_mfma_f32_16x16x32_f16(AF[4], B0, a_g, 0, 0, 0);
                a_g = __builtin_amdgcn_mfma_f32_16x16x32_f16(AF[5], B1, a_g, 0, 0, 0);
                a_o = __builtin_amdgcn_mfma_f32_16x16x32_f16(AF[6], B0, a_o, 0, 0, 0);
                a_o = __builtin_amdgcn_mfma_f32_16x16x32_f16(AF[7], B1, a_o, 0, 0, 0);
                __builtin_amdgcn_s_setprio(0);
                #pragma unroll
                for (int r = 0; r < 4; ++r)
                    if (pwok[r]) {
                        f32x4 v = {a_i[r], a_f[r], a_g[r], a_o[r]};
                        *(f32x4*)(lds + pw[r]) = v;
                    }
            }
            if (dopf)
                *(_Float16*)(lds + vaddr(BASE0, RB0, wb, nb, (52 + f) * 2)) = pfh;
        } else {
            const bool act = (g == 1) ? (n >= 1 && n <= Td) : (n >= 2);
            if (act) {
                if (ncol < NBb) {
                    Bv0 = *(const f16x8*)(lds + rd12[0] + rP12);
                    Bv1 = *(const f16x8*)(lds + rd12[1] + rP12);
                    Bv2 = *(const f16x8*)(lds + rd12[2] + rP12);
                    Bv3 = *(const f16x8*)(lds + rd12[3] + rP12);
                }
                f32x4 a_i = Z, a_f = Z, a_g = Z, a_o = Z;
                __builtin_amdgcn_s_setprio(1);
                a_i = __builtin_amdgcn_mfma_f32_16x16x32_f16(AF[0],  Bv0, a_i, 0, 0, 0);
                a_f = __builtin_amdgcn_mfma_f32_16x16x32_f16(AF[4],  Bv0, a_f, 0, 0, 0);
                a_g = __builtin_amdgcn_mfma_f32_16x16x32_f16(AF[8],  Bv0, a_g, 0, 0, 0);
                a_o = __builtin_amdgcn_mfma_f32_16x16x32_f16(AF[12], Bv0, a_o, 0, 0, 0);
                a_i = __builtin_amdgcn_mfma_f32_16x16x32_f16(AF[1],  Bv1, a_i, 0, 0, 0);
                a_f = __builtin_amdgcn_mfma_f32_16x16x32_f16(AF[5],  Bv1, a_f, 0, 0, 0);
                a_g = __builtin_amdgcn_mfma_f32_16x16x32_f16(AF[9],  Bv1, a_g, 0, 0, 0);
                a_o = __builtin_amdgcn_mfma_f32_16x16x32_f16(AF[13], Bv1, a_o, 0, 0, 0);
                a_i = __builtin_amdgcn_mfma_f32_16x16x32_f16(AF[2],  Bv2, a_i, 0, 0, 0);
                a_f = __builtin_amdgcn_mfma_f32_16x16x32_f16(AF[6],  Bv2, a_f, 0, 0, 0);
                a_g = __builtin_amdgcn_mfma_f32_16x16x32_f16(AF[10], Bv2, a_g, 0, 0, 0);
                a_o = __builtin_amdgcn_mfma_f32_16x16x32_f16(AF[14], Bv2, a_o, 0, 0, 0);
                a_i = __builtin_amdgcn_mfma_f32_16x16x32_f16(AF[3],  Bv3, a_i, 0, 0, 0);
                a_f = __builtin_amdgcn_mfma_f32_16x16x32_f16(AF[7],  Bv3, a_f, 0, 0, 0);
                a_g = __builtin_amdgcn_mfma_f32_16x16x32_f16(AF[11], Bv3, a_g, 0, 0, 0);
                a_o = __builtin_amdgcn_mfma_f32_16x16x32_f16(AF[15], Bv3, a_o, 0, 0, 0);
                __builtin_amdgcn_s_setprio(0);
                #pragma unroll
                for (int r = 0; r < 4; ++r)
                    if (pwok[r]) {
                        f32x4 v = {a_i[r], a_f[r], a_g[r], a_o[r]};
                        *(f32x4*)(lds + pw[r]) = v;
                    }
                if (g == 2 && w == 11 && kg == 1 && ncol < NBb && n >= 3) {
                    // head rows 52,53 live in gs=0 tile c=3, C rows 4,5 -> kg=1, r=0,1
                    float mean = a_i[0];
                    float spre = a_i[1];
                    float sp = (spre > 30.f) ? spre : __logf(1.f + __expf(spre));
                    const int t = n - 3;
                    float2 o2 = make_float2(mean, sp);
                    *(float2*)&g_out[((size_t)(b0 + ncol) * Td + t) * 2] = o2;
                }
            }
        }
        __syncthreads();   // preacts (and x) visible

        // ================= update phase (1 cell per thread) =================
        if (uok) {
            const int t_u = n - ul;
            if (t_u >= 0 && t_u < Td) {
                f32x4 v = *(const f32x4*)(lds + prd);
                float si = sigm2(v[0]);
                float sf = sigm2(v[1]);
                float gg = tanh2(v[2]);
                float go = sigm2(v[3]);
                float cn = fmaf(sf, ucs, si * gg);
                ucs = cn;
                _Float16 hf = (_Float16)(go * tanh_c(cn));
                *(_Float16*)(lds + wh1 + wb * str1) = hf;
                if (has2) *(_Float16*)(lds + wh2 + wb * PAR12) = hf;
            }
        }
        __syncthreads();   // h visible for next iteration
    }
}

extern "C" void kernel_launch(void* const* d_in, const int* in_sizes, int n_in,
                              void* d_out, int out_size, void* d_ws, size_t ws_size,
                              hipStream_t stream) {
    const float* input = (const float*)d_in[0];
    const float* timei = (const float*)d_in[1];
    const float* Wih0  = (const float*)d_in[2];
    const float* Whh0  = (const float*)d_in[3];
    const float* bih0  = (const float*)d_in[4];
    const float* bhh0  = (const float*)d_in[5];
    const float* Wih1  = (const float*)d_in[6];
    const float* Whh1  = (const float*)d_in[7];
    const float* bih1  = (const float*)d_in[8];
    const float* bhh1  = (const float*)d_in[9];
    const float* Wih2  = (const float*)d_in[10];
    const float* Whh2  = (const float*)d_in[11];
    const float* bih2  = (const float*)d_in[12];
    const float* bhh2  = (const float*)d_in[13];
    const float* Wlin  = (const float*)d_in[14];
    const float* blin  = (const float*)d_in[15];
    float* out = (float*)d_out;

    lstm3_mfma<<<dim3(NBLK), dim3(NTH), 0, stream>>>(
        input, timei,
        Wih0, Whh0, bih0, bhh0,
        Wih1, Whh1, bih1, bhh1,
        Wih2, Whh2, bih2, bhh2,
        Wlin, blin, out);
}

// Round 15
// 18899.295 us; speedup vs baseline: 1.0010x; 1.0010x over previous
//
#include <hip/hip_runtime.h>
#include <cstddef>
#include <cstdint>

#define Hd 51
#define Td 2048
#define NBb 2       // batches per block
#define NTH 768     // 12 waves: 4xL0, 4xL1, 4xL2 (one of each per SIMD)
#define NBLK 512    // 2 blocks per CU -> cross-block phase overlap

typedef _Float16 f16x8 __attribute__((ext_vector_type(8)));
typedef _Float16 f16x4 __attribute__((ext_vector_type(4)));
typedef float    f32x4 __attribute__((ext_vector_type(4)));

// LDS layout identical to R13 (64 KB; 2 blocks x 64KB = 128KB <= 160KB/CU):
//  buf0/1/2: double-buffered h panels, chunk-transposed (16B chunks @256B)
//  PRE: preact exchange [l][c] blocks of 64 slots x 16B (f32x4 {i,f,g,o})
//  XP : whole-sequence x panel, f16, xp[t][slot], slot = f*4+n
#define RB0   128
#define RB12  256
#define BASE0 0
#define BASE1 4096
#define BASE2 12288
#define PRE   20480
#define XP    32768
#define LDSB  65536

#define LOG2E  1.44269504f
#define LOG2E2 2.88539008f

__device__ __forceinline__ int vaddr(int base, int rowB, int db, int n, int off) {
    return base + db * (16 * rowB) + ((off >> 4) << 8) + (n << 4) + (off & 15);
}

// preact slot: bijective (m4 = elem&15, n) <-> slot
__device__ __forceinline__ int pslot(int m4, int n) {
    return ((m4 ^ n) & 15) | (n << 4);
}

__device__ __forceinline__ float fast_rcp(float x) { return __builtin_amdgcn_rcpf(x); }
__device__ __forceinline__ float exp2_fast(float x) {
#if __has_builtin(__builtin_amdgcn_exp2f)
    return __builtin_amdgcn_exp2f(x);
#else
    return exp2f(x);
#endif
}

// preactivations arrive PRE-SCALED: a' = a*log2e (i,f,o) or a*2*log2e (g)
__device__ __forceinline__ float sigm2(float ap)  { return fast_rcp(1.f + exp2_fast(-ap)); }
__device__ __forceinline__ float tanh2(float ap)  { return fmaf(2.f, fast_rcp(1.f + exp2_fast(-ap)), -1.f); }
__device__ __forceinline__ float tanh_c(float x) {   // x in true units
    float e = exp2_fast(-LOG2E2 * fabsf(x));
    float t = (1.f - e) * fast_rcp(1.f + e);
    return copysignf(t, x);
}

__global__ __launch_bounds__(NTH, 6)   // 6 waves/SIMD -> VGPR <= 85 (2 blocks/CU)
void lstm3_mfma(const float* __restrict__ g_input, const float* __restrict__ g_time,
                const float* __restrict__ Wih0, const float* __restrict__ Whh0,
                const float* __restrict__ bih0, const float* __restrict__ bhh0,
                const float* __restrict__ Wih1, const float* __restrict__ Whh1,
                const float* __restrict__ bih1, const float* __restrict__ bhh1,
                const float* __restrict__ Wih2, const float* __restrict__ Whh2,
                const float* __restrict__ bih2, const float* __restrict__ bhh2,
                const float* __restrict__ Wlin, const float* __restrict__ blin,
                float* __restrict__ g_out)
{
    __shared__ __align__(16) unsigned char lds[LDSB];

    const int tid  = threadIdx.x;
    const int lane = tid & 63;
    const int w    = tid >> 6;       // wave 0..11
    const int g    = w >> 2;         // layer group: 0=L0, 1=L1, 2=L2
    const int c    = w & 3;          // element-chunk (16 gate-elements / tile set)
    const int ncol = lane & 15;      // batch col (B) / A-row-in-tile
    const int kg   = lane >> 4;      // k-group 0..3
    const int b0   = blockIdx.x * NBb;

    // ---- zero LDS (h buffers must be 0) ----
    for (int i = tid * 4; i < LDSB; i += NTH * 4) *(uint32_t*)(lds + i) = 0u;
    __syncthreads();

    // one-slots (bias column of B) in BOTH double buffers; x(t=0)
    if (tid < 32) {
        int db = tid >> 4, n = tid & 15;
        *(unsigned short*)(lds + vaddr(BASE0, RB0,  db, n,  54 * 2)) = 0x3C00; // f16 1.0
        *(unsigned short*)(lds + vaddr(BASE1, RB12, db, n, 112 * 2)) = 0x3C00;
        *(unsigned short*)(lds + vaddr(BASE2, RB12, db, n, 112 * 2)) = 0x3C00;
    } else if (tid >= 64 && tid < 68) {
        int i = tid - 64; int n = i & 1, f = i >> 1;
        const float* src = f ? g_time : g_input;
        float v = src[(size_t)(b0 + n) * Td];
        *(_Float16*)(lds + vaddr(BASE0, RB0, 0, n, (52 + f) * 2)) = (_Float16)v;
    }

    // ---- preload ALL x into XP panel (coalesced float4, one-time) ----
    // chunks: 2 feat x 2 batch x 512 float4 = 2048
    for (int i = tid; i < 2048; i += NTH) {
        const int f  = i >> 10;
        const int rm = i & 1023;
        const int n  = rm >> 9;
        const int t4 = rm & 511;
        const float* src = f ? g_time : g_input;
        float4 v = *(const float4*)&src[(size_t)(b0 + n) * Td + 4 * t4];
        const int slot = f * 4 + n;
        #pragma unroll
        for (int j = 0; j < 4; ++j)
            *(_Float16*)(lds + XP + ((((4 * t4 + j) << 3) + slot) << 1)) = (_Float16)((&v.x)[j]);
    }

    // ---- load weight A-fragments (f16, log2e-prescaled) ----
    // A-frag lane map (16x16x32): row = 16*tile + (lane&15), k = 32*s + 8*(lane>>4) + e
    // wave owns tiles {c, c+4, c+8, c+12}: gate gs rows = 64*gs + er, er = 16c + ncol
    const int er = 16 * c + ncol;
    const bool rvalid = (er < Hd);
    f16x8 AF[16];   // g0: [0..7] = 4 gates x 2 ksteps; g1/g2: [0..15] = 4 gates x 4 ksteps

    if (g == 0) {
        #pragma unroll
        for (int gs = 0; gs < 4; ++gs) {
            const int sr = gs * Hd + er;
            const float S = (gs == 2) ? LOG2E2 : LOG2E;   // g-gate: tanh(a)=2sig(2a)-1
            #pragma unroll
            for (int s = 0; s < 2; ++s)
                #pragma unroll
                for (int e = 0; e < 8; ++e) {
                    const int kk = 32 * s + 8 * kg + e;
                    float v = 0.f;
                    if (rvalid) {
                        if (kk < 51)                   v = Whh0[sr * 51 + kk];
                        else if (kk == 52 || kk == 53) v = Wih0[sr * 2 + (kk - 52)];
                        else if (kk == 54)             v = bih0[sr] + bhh0[sr];
                    }
                    AF[gs * 2 + s][e] = (_Float16)(v * S);
                }
        }
    } else {
        const float* Wih = (g == 1) ? Wih1 : Wih2;   // prev-layer h (k 0..50)
        const float* Whh = (g == 1) ? Whh1 : Whh2;   // own h (k 56..106)
        const float* bihp = (g == 1) ? bih1 : bih2;
        const float* bhhp = (g == 1) ? bhh1 : bhh2;
        #pragma unroll
        for (int gs = 0; gs < 4; ++gs) {
            const int sr = gs * Hd + er;
            const float S = (gs == 2) ? LOG2E2 : LOG2E;
            #pragma unroll
            for (int s = 0; s < 4; ++s)
                #pragma unroll
                for (int e = 0; e < 8; ++e) {
                    const int kk = 32 * s + 8 * kg + e;
                    float v = 0.f;
                    float sc = S;
                    if (rvalid) {
                        if (kk < 51)                   v = Wih[sr * 51 + kk];
                        else if (kk >= 56 && kk < 107) v = Whh[sr * 51 + (kk - 56)];
                        else if (kk == 112)            v = bihp[sr] + bhhp[sr];
                    } else if (g == 2 && gs == 0 && (er == 52 || er == 53)) {
                        const int hr = er - 52;        // head rows: LINEAR, unscaled
                        sc = 1.f;
                        if (kk >= 56 && kk < 107)      v = Wlin[hr * 51 + (kk - 56)];
                        else if (kk == 112)            v = blin[hr];
                    }
                    AF[gs * 4 + s][e] = (_Float16)(v * sc);
                }
        }
    }

    // ---- hoisted MFMA-phase addresses ----
    const f32x4 Z = {0.f, 0.f, 0.f, 0.f};
    const int PAR0 = 16 * RB0;    // db stride buf0
    const int PAR12 = 16 * RB12;  // db stride buf1/2
    int rd0a = vaddr(BASE0, RB0, 0, ncol, 16 * kg);
    int rd0b = vaddr(BASE0, RB0, 0, ncol, 64 + 16 * kg);
    int rd12[4];
    {
        const int baseg = (g == 2) ? BASE2 : BASE1;
        #pragma unroll
        for (int s = 0; s < 4; ++s) rd12[s] = vaddr(baseg, RB12, 0, ncol, 64 * s + 16 * kg);
    }
    // preact write addrs (one per C row r); valid iff ncol<NBb && e0+r<51
    const int e0 = 16 * c + 4 * kg;
    int pw[4];
    bool pwok[4];
    #pragma unroll
    for (int r = 0; r < 4; ++r) {
        pw[r] = PRE + ((g * 4 + c) << 10) + (pslot(4 * kg + r, ncol & 3) << 4);
        pwok[r] = (ncol < NBb) && (e0 + r < Hd);
    }

    // ---- update-thread decode: u = w*26 + lane (lane<26), 306 cells ----
    const int u = w * 26 + lane;
    const bool uok = (lane < 26) && (u < 3 * Hd * NBb);
    int ul = 0, prd = 0, wh1 = 0, wh2 = 0, str1 = 0;
    bool has2 = false;
    if (uok) {
        ul = u / (Hd * NBb);             // layer 0..2 (may diverge in boundary waves)
        const int rr = u - ul * (Hd * NBb);
        const int ue = rr >> 1;          // element 0..50
        const int un = rr & 1;           // batch 0..1
        prd = PRE + ((ul * 4 + (ue >> 4)) << 10) + (pslot(ue & 15, un) << 4);
        if (ul == 0) {
            wh1 = vaddr(BASE0, RB0,  0, un, 2 * ue);       str1 = PAR0;
            wh2 = vaddr(BASE1, RB12, 0, un, 2 * ue);       has2 = true;
        } else if (ul == 1) {
            wh1 = vaddr(BASE1, RB12, 0, un, 112 + 2 * ue); str1 = PAR12;
            wh2 = vaddr(BASE2, RB12, 0, un, 2 * ue);       has2 = true;
        } else {
            wh1 = vaddr(BASE2, RB12, 0, un, 112 + 2 * ue); str1 = PAR12;
        }
    }
    float ucs = 0.f;   // persistent c-state of this thread's cell

    // loop-carried B operands: lanes ncol>=NBb stay ZERO forever (masked reads)
    f16x8 zf;
    #pragma unroll
    for (int e = 0; e < 8; ++e) zf[e] = (_Float16)0.f;
    f16x8 B0 = zf, B1 = zf;                        // g0
    f16x8 Bv0 = zf, Bv1 = zf, Bv2 = zf, Bv3 = zf;  // g1/g2

    __syncthreads();

    // layer skew: iter n computes L0@t=n, L1@t=n-1, L2@t=n-2, head@t=n-3
    for (int n = 0; n <= Td + 2; ++n) {
        const int rb = n & 1, wb = rb ^ 1;
        const int rP0 = rb * PAR0, rP12 = rb * PAR12;

        // ================= MFMA phase =================
        if (g == 0) {
            const bool dopf = (w == 0 && lane < 8 && (n + 1) < Td);
            _Float16 pfh = (_Float16)0.f;
            const int nb = lane & 3, f = lane >> 2;
            if (dopf)   // x from LDS panel: ~30cyc, never stalls the barrier
                pfh = *(const _Float16*)(lds + XP + ((((n + 1) << 3) + lane) << 1));
            if (n < Td) {
                if (ncol < NBb) {   // masked: only real batch columns hit LDS
                    B0 = *(const f16x8*)(lds + rd0a + rP0);
                    B1 = *(const f16x8*)(lds + rd0b + rP0);
                }
                f32x4 a_i = Z, a_f = Z, a_g = Z, a_o = Z;
                __builtin_amdgcn_s_setprio(1);
                a_i = __builtin_amdgcn_mfma_f32_16x16x32_f16(AF[0], B0, a_i, 0, 0, 0);
                a_i = __builtin_amdgcn_mfma_f32_16x16x32_f16(AF[1], B1, a_i, 0, 0, 0);
                a_f = __builtin_amdgcn_mfma_f32_16x16x32_f16(AF[2], B0, a_f, 0, 0, 0);
                a_f = __builtin_amdgcn_mfma_f32_16x16x32_f16(AF[3], B1, a_f, 0, 0, 0);
                a_g = __builtin_amdgcn_mfma_f32_16x16x32_f16(AF[4], B0, a_g, 0, 0, 0);
                a_g = __builtin_amdgcn_mfma_f32_16x16x32_f16(AF[5], B1, a_g, 0, 0, 0);
                a_o = __builtin_amdgcn_mfma_f32_16x16x32_f16(AF[6], B0, a_o, 0, 0, 0);
                a_o = __builtin_amdgcn_mfma_f32_16x16x32_f16(AF[7], B1, a_o, 0, 0, 0);
                __builtin_amdgcn_s_setprio(0);
                #pragma unroll
                for (int r = 0; r < 4; ++r)
                    if (pwok[r]) {
                        f32x4 v = {a_i[r], a_f[r], a_g[r], a_o[r]};
                        *(f32x4*)(lds + pw[r]) = v;
                    }
            }
            if (dopf)
                *(_Float16*)(lds + vaddr(BASE0, RB0, wb, nb, (52 + f) * 2)) = pfh;
        } else {
            const bool act = (g == 1) ? (n >= 1 && n <= Td) : (n >= 2);
            if (act) {
                if (ncol < NBb) {
                    Bv0 = *(const f16x8*)(lds + rd12[0] + rP12);
                    Bv1 = *(const f16x8*)(lds + rd12[1] + rP12);
                    Bv2 = *(const f16x8*)(lds + rd12[2] + rP12);
                    Bv3 = *(const f16x8*)(lds + rd12[3] + rP12);
                }
                f32x4 a_i = Z, a_f = Z, a_g = Z, a_o = Z;
                __builtin_amdgcn_s_setprio(1);
                a_i = __builtin_amdgcn_mfma_f32_16x16x32_f16(AF[0],  Bv0, a_i, 0, 0, 0);
                a_f = __builtin_amdgcn_mfma_f32_16x16x32_f16(AF[4],  Bv0, a_f, 0, 0, 0);
                a_g = __builtin_amdgcn_mfma_f32_16x16x32_f16(AF[8],  Bv0, a_g, 0, 0, 0);
                a_o = __builtin_amdgcn_mfma_f32_16x16x32_f16(AF[12], Bv0, a_o, 0, 0, 0);
                a_i = __builtin_amdgcn_mfma_f32_16x16x32_f16(AF[1],  Bv1, a_i, 0, 0, 0);
                a_f = __builtin_amdgcn_mfma_f32_16x16x32_f16(AF[5],  Bv1, a_f, 0, 0, 0);
                a_g = __builtin_amdgcn_mfma_f32_16x16x32_f16(AF[9],  Bv1, a_g, 0, 0, 0);
                a_o = __builtin_amdgcn_mfma_f32_16x16x32_f16(AF[13], Bv1, a_o, 0, 0, 0);
                a_i = __builtin_amdgcn_mfma_f32_16x16x32_f16(AF[2],  Bv2, a_i, 0, 0, 0);
                a_f = __builtin_amdgcn_mfma_f32_16x16x32_f16(AF[6],  Bv2, a_f, 0, 0, 0);
                a_g = __builtin_amdgcn_mfma_f32_16x16x32_f16(AF[10], Bv2, a_g, 0, 0, 0);
                a_o = __builtin_amdgcn_mfma_f32_16x16x32_f16(AF[14], Bv2, a_o, 0, 0, 0);
                a_i = __builtin_amdgcn_mfma_f32_16x16x32_f16(AF[3],  Bv3, a_i, 0, 0, 0);
                a_f = __builtin_amdgcn_mfma_f32_16x16x32_f16(AF[7],  Bv3, a_f, 0, 0, 0);
                a_g = __builtin_amdgcn_mfma_f32_16x16x32_f16(AF[11], Bv3, a_g, 0, 0, 0);
                a_o = __builtin_amdgcn_mfma_f32_16x16x32_f16(AF[15], Bv3, a_o, 0, 0, 0);
                __builtin_amdgcn_s_setprio(0);
                #pragma unroll
                for (int r = 0; r < 4; ++r)
                    if (pwok[r]) {
                        f32x4 v = {a_i[r], a_f[r], a_g[r], a_o[r]};
                        *(f32x4*)(lds + pw[r]) = v;
                    }
                if (g == 2 && w == 11 && kg == 1 && ncol < NBb && n >= 3) {
                    // head rows 52,53 live in gs=0 tile c=3, C rows 4,5 -> kg=1, r=0,1
                    float mean = a_i[0];
                    float spre = a_i[1];
                    float sp = (spre > 30.f) ? spre : __logf(1.f + __expf(spre));
                    const int t = n - 3;
                    float2 o2 = make_float2(mean, sp);
                    *(float2*)&g_out[((size_t)(b0 + ncol) * Td + t) * 2] = o2;
                }
            }
        }
        __syncthreads();   // preacts (and x) visible

        // ================= update phase (1 cell per thread) =================
        if (uok) {
            const int t_u = n - ul;
            if (t_u >= 0 && t_u < Td) {
                f32x4 v = *(const f32x4*)(lds + prd);
                float si = sigm2(v[0]);
                float sf = sigm2(v[1]);
                float gg = tanh2(v[2]);
                float go = sigm2(v[3]);
                float cn = fmaf(sf, ucs, si * gg);
                ucs = cn;
                _Float16 hf = (_Float16)(go * tanh_c(cn));
                *(_Float16*)(lds + wh1 + wb * str1) = hf;
                if (has2) *(_Float16*)(lds + wh2 + wb * PAR12) = hf;
            }
        }
        __syncthreads();   // h visible for next iteration
    }
}

extern "C" void kernel_launch(void* const* d_in, const int* in_sizes, int n_in,
                              void* d_out, int out_size, void* d_ws, size_t ws_size,
                              hipStream_t stream) {
    const float* input = (const float*)d_in[0];
    const float* timei = (const float*)d_in[1];
    const float* Wih0  = (const float*)d_in[2];
    const float* Whh0  = (const float*)d_in[3];
    const float* bih0  = (const float*)d_in[4];
    const float* bhh0  = (const float*)d_in[5];
    const float* Wih1  = (const float*)d_in[6];
    const float* Whh1  = (const float*)d_in[7];
    const float* bih1  = (const float*)d_in[8];
    const float* bhh1  = (const float*)d_in[9];
    const float* Wih2  = (const float*)d_in[10];
    const float* Whh2  = (const float*)d_in[11];
    const float* bih2  = (const float*)d_in[12];
    const float* bhh2  = (const float*)d_in[13];
    const float* Wlin  = (const float*)d_in[14];
    const float* blin  = (const float*)d_in[15];
    float* out = (float*)d_out;

    lstm3_mfma<<<dim3(NBLK), dim3(NTH), 0, stream>>>(
        input, timei,
        Wih0, Whh0, bih0, bhh0,
        Wih1, Whh1, bih1, bhh1,
        Wih2, Whh2, bih2, bhh2,
        Wlin, blin, out);
}

// Round 16
// 1713.954 us; speedup vs baseline: 11.0376x; 11.0267x over previous
//
#include <hip/hip_runtime.h>
#include <cstddef>
#include <cstdint>

#define Hd 51
#define Td 2048
#define NBb 4       // batches per block
#define NTH 768     // 12 waves: 4xL0, 4xL1, 4xL2 (one of each per SIMD)
#define NBLK 256    // full chip

typedef _Float16 f16x8 __attribute__((ext_vector_type(8)));
typedef _Float16 f16x4 __attribute__((ext_vector_type(4)));
typedef float    f32x4 __attribute__((ext_vector_type(4)));

// LDS map (identical to R13):
//  buf0/1/2: double-buffered h panels, chunk-transposed (16B chunks @256B)
//  PRE: per-WAVE private preact transpose blocks [g*4+c] of 64 slots x 16B.
//       Written and read by the SAME wave within one interval -> NO barrier;
//       ordering enforced by s_waitcnt lgkmcnt(0) + sched_barrier.
//  XP : whole-sequence x panel, f16, xp[t][slot], slot = f*4+n
#define RB0   128
#define RB12  256
#define BASE0 0
#define BASE1 4096
#define BASE2 12288
#define PRE   20480
#define XP    32768
#define LDSB  65536

#define LOG2E  1.44269504f
#define LOG2E2 2.88539008f

__device__ __forceinline__ int vaddr(int base, int rowB, int db, int n, int off) {
    return base + db * (16 * rowB) + ((off >> 4) << 8) + (n << 4) + (off & 15);
}

// preact slot: bijective (m4 = elem&15, n) <-> slot; writer==reader wave
__device__ __forceinline__ int pslot(int m4, int n) {
    return ((m4 ^ n) & 15) | (n << 4);
}

__device__ __forceinline__ float fast_rcp(float x) { return __builtin_amdgcn_rcpf(x); }
__device__ __forceinline__ float exp2_fast(float x) {
#if __has_builtin(__builtin_amdgcn_exp2f)
    return __builtin_amdgcn_exp2f(x);
#else
    return exp2f(x);
#endif
}

// preactivations arrive PRE-SCALED: a' = a*log2e (i,f,o) or a*2*log2e (g)
__device__ __forceinline__ float sigm2(float ap)  { return fast_rcp(1.f + exp2_fast(-ap)); }
__device__ __forceinline__ float tanh2(float ap)  { return fmaf(2.f, fast_rcp(1.f + exp2_fast(-ap)), -1.f); }
__device__ __forceinline__ float tanh_c(float x) {   // x in true units
    float e = exp2_fast(-LOG2E2 * fabsf(x));
    float t = (1.f - e) * fast_rcp(1.f + e);
    return copysignf(t, x);
}

__global__ __launch_bounds__(NTH, 3)
void lstm3_mfma(const float* __restrict__ g_input, const float* __restrict__ g_time,
                const float* __restrict__ Wih0, const float* __restrict__ Whh0,
                const float* __restrict__ bih0, const float* __restrict__ bhh0,
                const float* __restrict__ Wih1, const float* __restrict__ Whh1,
                const float* __restrict__ bih1, const float* __restrict__ bhh1,
                const float* __restrict__ Wih2, const float* __restrict__ Whh2,
                const float* __restrict__ bih2, const float* __restrict__ bhh2,
                const float* __restrict__ Wlin, const float* __restrict__ blin,
                float* __restrict__ g_out)
{
    __shared__ __align__(16) unsigned char lds[LDSB];

    const int tid  = threadIdx.x;
    const int lane = tid & 63;
    const int w    = tid >> 6;       // wave 0..11
    const int g    = w >> 2;         // layer group: 0=L0, 1=L1, 2=L2
    const int c    = w & 3;          // element-chunk (16 gate-elements / tile set)
    const int ncol = lane & 15;      // batch col (B) / A-row-in-tile
    const int kg   = lane >> 4;      // k-group 0..3
    const int b0   = blockIdx.x * NBb;

    // ---- zero LDS (h buffers must be 0) ----
    for (int i = tid * 4; i < LDSB; i += NTH * 4) *(uint32_t*)(lds + i) = 0u;
    __syncthreads();

    // one-slots (bias column of B) in BOTH double buffers; x(t=0)
    if (tid < 32) {
        int db = tid >> 4, n = tid & 15;
        *(unsigned short*)(lds + vaddr(BASE0, RB0,  db, n,  54 * 2)) = 0x3C00; // f16 1.0
        *(unsigned short*)(lds + vaddr(BASE1, RB12, db, n, 112 * 2)) = 0x3C00;
        *(unsigned short*)(lds + vaddr(BASE2, RB12, db, n, 112 * 2)) = 0x3C00;
    } else if (tid >= 64 && tid < 72) {
        int i = tid - 64; int n = i & 3, f = i >> 2;
        const float* src = f ? g_time : g_input;
        float v = src[(size_t)(b0 + n) * Td];
        *(_Float16*)(lds + vaddr(BASE0, RB0, 0, n, (52 + f) * 2)) = (_Float16)v;
    }

    // ---- preload ALL x into XP panel (coalesced float4, one-time) ----
    for (int i = tid; i < 4096; i += NTH) {
        const int f  = i >> 11;
        const int rm = i & 2047;
        const int n  = rm >> 9;
        const int t4 = rm & 511;
        const float* src = f ? g_time : g_input;
        float4 v = *(const float4*)&src[(size_t)(b0 + n) * Td + 4 * t4];
        const int slot = f * 4 + n;
        #pragma unroll
        for (int j = 0; j < 4; ++j)
            *(_Float16*)(lds + XP + ((((4 * t4 + j) << 3) + slot) << 1)) = (_Float16)((&v.x)[j]);
    }

    // ---- load weight A-fragments (f16, log2e-prescaled) ----
    // A-frag lane map (16x16x32): row = 16*tile + (lane&15), k = 32*s + 8*(lane>>4) + e
    // wave owns tiles {c, c+4, c+8, c+12}: gate gs rows = 64*gs + er, er = 16c + ncol
    const int er = 16 * c + ncol;
    const bool rvalid = (er < Hd);
    f16x8 AF[16];   // g0: [0..7] = 4 gates x 2 ksteps; g1/g2: [0..15] = 4 gates x 4 ksteps

    if (g == 0) {
        #pragma unroll
        for (int gs = 0; gs < 4; ++gs) {
            const int sr = gs * Hd + er;
            const float S = (gs == 2) ? LOG2E2 : LOG2E;   // g-gate: tanh(a)=2sig(2a)-1
            #pragma unroll
            for (int s = 0; s < 2; ++s)
                #pragma unroll
                for (int e = 0; e < 8; ++e) {
                    const int kk = 32 * s + 8 * kg + e;
                    float v = 0.f;
                    if (rvalid) {
                        if (kk < 51)                   v = Whh0[sr * 51 + kk];
                        else if (kk == 52 || kk == 53) v = Wih0[sr * 2 + (kk - 52)];
                        else if (kk == 54)             v = bih0[sr] + bhh0[sr];
                    }
                    AF[gs * 2 + s][e] = (_Float16)(v * S);
                }
        }
    } else {
        const float* Wih = (g == 1) ? Wih1 : Wih2;   // prev-layer h (k 0..50)
        const float* Whh = (g == 1) ? Whh1 : Whh2;   // own h (k 56..106)
        const float* bihp = (g == 1) ? bih1 : bih2;
        const float* bhhp = (g == 1) ? bhh1 : bhh2;
        #pragma unroll
        for (int gs = 0; gs < 4; ++gs) {
            const int sr = gs * Hd + er;
            const float S = (gs == 2) ? LOG2E2 : LOG2E;
            #pragma unroll
            for (int s = 0; s < 4; ++s)
                #pragma unroll
                for (int e = 0; e < 8; ++e) {
                    const int kk = 32 * s + 8 * kg + e;
                    float v = 0.f;
                    float sc = S;
                    if (rvalid) {
                        if (kk < 51)                   v = Wih[sr * 51 + kk];
                        else if (kk >= 56 && kk < 107) v = Whh[sr * 51 + (kk - 56)];
                        else if (kk == 112)            v = bihp[sr] + bhhp[sr];
                    } else if (g == 2 && gs == 0 && (er == 52 || er == 53)) {
                        const int hr = er - 52;        // head rows: LINEAR, unscaled
                        sc = 1.f;
                        if (kk >= 56 && kk < 107)      v = Wlin[hr * 51 + (kk - 56)];
                        else if (kk == 112)            v = blin[hr];
                    }
                    AF[gs * 4 + s][e] = (_Float16)(v * sc);
                }
        }
    }

    // ---- hoisted addresses ----
    const f32x4 Z = {0.f, 0.f, 0.f, 0.f};
    const int PAR0 = 16 * RB0;    // db stride buf0
    const int PAR12 = 16 * RB12;  // db stride buf1/2
    int rd0a = vaddr(BASE0, RB0, 0, ncol, 16 * kg);
    int rd0b = vaddr(BASE0, RB0, 0, ncol, 64 + 16 * kg);
    int rd12[4];
    {
        const int baseg = (g == 2) ? BASE2 : BASE1;
        #pragma unroll
        for (int s = 0; s < 4; ++s) rd12[s] = vaddr(baseg, RB12, 0, ncol, 64 * s + 16 * kg);
    }
    // preact write addrs (one per C row r); g2 includes head rows 52,53
    const int e0 = 16 * c + 4 * kg;
    const int elim = (g == 2) ? 54 : Hd;
    int pw[4];
    bool pwok[4];
    #pragma unroll
    for (int r = 0; r < 4; ++r) {
        pw[r] = PRE + ((g * 4 + c) << 10) + (pslot(4 * kg + r, ncol & 3) << 4);
        pwok[r] = (ncol < NBb) && (e0 + r < elim);
    }
    // wave-local transposed read: lane holds cell (eg = 16c + el, b = lane>>4)
    const int el = lane & 15;
    const int ub = lane >> 4;            // batch 0..3
    const int eg = 16 * c + el;          // element 0..63 (valid < 51)
    const int prd = PRE + ((g * 4 + c) << 10) + (pslot(el, ub) << 4);
    const bool upd_ok = (eg < Hd);
    const bool head_ok = (g == 2 && c == 3 && (el == 4 || el == 5)); // eg 52,53
    int wh1, wh2 = -1, str1;
    if (g == 0) {
        wh1 = vaddr(BASE0, RB0,  0, ub, 2 * eg);       str1 = PAR0;
        wh2 = vaddr(BASE1, RB12, 0, ub, 2 * eg);
    } else if (g == 1) {
        wh1 = vaddr(BASE1, RB12, 0, ub, 112 + 2 * eg); str1 = PAR12;
        wh2 = vaddr(BASE2, RB12, 0, ub, 2 * eg);
    } else {
        wh1 = vaddr(BASE2, RB12, 0, ub, 112 + 2 * eg); str1 = PAR12;
    }
    float ucs = 0.f;   // this lane's persistent c-state

    // loop-carried B operands: lanes ncol>=NBb stay ZERO forever (masked reads)
    f16x8 zf;
    #pragma unroll
    for (int e = 0; e < 8; ++e) zf[e] = (_Float16)0.f;
    f16x8 B0 = zf, B1 = zf;                        // g0
    f16x8 Bv0 = zf, Bv1 = zf, Bv2 = zf, Bv3 = zf;  // g1/g2

    __syncthreads();

    // layer skew: iter n computes L0@t=n, L1@t=n-1, L2@t=n-2, head@t=n-3
    // SINGLE barrier per iteration: preact transpose is wave-local.
    for (int n = 0; n <= Td + 2; ++n) {
        const int rb = n & 1, wb = rb ^ 1;
        const int rP0 = rb * PAR0, rP12 = rb * PAR12;
        const int wP12 = wb * PAR12;

        if (g == 0) {
            const bool dopf = (w == 0 && lane < 8 && (n + 1) < Td);
            _Float16 pfh = (_Float16)0.f;
            const int nb = lane & 3, f = lane >> 2;
            if (dopf)
                pfh = *(const _Float16*)(lds + XP + ((((n + 1) << 3) + lane) << 1));
            if (n < Td) {
                if (ncol < NBb) {
                    B0 = *(const f16x8*)(lds + rd0a + rP0);
                    B1 = *(const f16x8*)(lds + rd0b + rP0);
                }
                f32x4 a_i = Z, a_f = Z, a_g = Z, a_o = Z;
                __builtin_amdgcn_s_setprio(1);
                a_i = __builtin_amdgcn_mfma_f32_16x16x32_f16(AF[0], B0, a_i, 0, 0, 0);
                a_i = __builtin_amdgcn_mfma_f32_16x16x32_f16(AF[1], B1, a_i, 0, 0, 0);
                a_f = __builtin_amdgcn_mfma_f32_16x16x32_f16(AF[2], B0, a_f, 0, 0, 0);
                a_f = __builtin_amdgcn_mfma_f32_16x16x32_f16(AF[3], B1, a_f, 0, 0, 0);
                a_g = __builtin_amdgcn_mfma_f32_16x16x32_f16(AF[4], B0, a_g, 0, 0, 0);
                a_g = __builtin_amdgcn_mfma_f32_16x16x32_f16(AF[5], B1, a_g, 0, 0, 0);
                a_o = __builtin_amdgcn_mfma_f32_16x16x32_f16(AF[6], B0, a_o, 0, 0, 0);
                a_o = __builtin_amdgcn_mfma_f32_16x16x32_f16(AF[7], B1, a_o, 0, 0, 0);
                __builtin_amdgcn_s_setprio(0);
                #pragma unroll
                for (int r = 0; r < 4; ++r)
                    if (pwok[r]) {
                        f32x4 v = {a_i[r], a_f[r], a_g[r], a_o[r]};
                        *(f32x4*)(lds + pw[r]) = v;
                    }
                // wave-local: order read after writes, wait DS pipe
                asm volatile("s_waitcnt lgkmcnt(0)" ::: "memory");
                __builtin_amdgcn_sched_barrier(0);
                f32x4 v = *(const f32x4*)(lds + prd);
                if (upd_ok) {           // t = n
                    float si = sigm2(v[0]);
                    float sf = sigm2(v[1]);
                    float gg = tanh2(v[2]);
                    float go = sigm2(v[3]);
                    float cn = fmaf(sf, ucs, si * gg);
                    ucs = cn;
                    _Float16 hf = (_Float16)(go * tanh_c(cn));
                    *(_Float16*)(lds + wh1 + wb * str1) = hf;
                    *(_Float16*)(lds + wh2 + wP12) = hf;
                }
            }
            if (dopf)
                *(_Float16*)(lds + vaddr(BASE0, RB0, wb, nb, (52 + f) * 2)) = pfh;
        } else {
            const bool act = (g == 1) ? (n >= 1 && n <= Td) : (n >= 2);
            if (act) {
                if (ncol < NBb) {
                    Bv0 = *(const f16x8*)(lds + rd12[0] + rP12);
                    Bv1 = *(const f16x8*)(lds + rd12[1] + rP12);
                    Bv2 = *(const f16x8*)(lds + rd12[2] + rP12);
                    Bv3 = *(const f16x8*)(lds + rd12[3] + rP12);
                }
                f32x4 a_i = Z, a_f = Z, a_g = Z, a_o = Z;
                __builtin_amdgcn_s_setprio(1);
                a_i = __builtin_amdgcn_mfma_f32_16x16x32_f16(AF[0],  Bv0, a_i, 0, 0, 0);
                a_f = __builtin_amdgcn_mfma_f32_16x16x32_f16(AF[4],  Bv0, a_f, 0, 0, 0);
                a_g = __builtin_amdgcn_mfma_f32_16x16x32_f16(AF[8],  Bv0, a_g, 0, 0, 0);
                a_o = __builtin_amdgcn_mfma_f32_16x16x32_f16(AF[12], Bv0, a_o, 0, 0, 0);
                a_i = __builtin_amdgcn_mfma_f32_16x16x32_f16(AF[1],  Bv1, a_i, 0, 0, 0);
                a_f = __builtin_amdgcn_mfma_f32_16x16x32_f16(AF[5],  Bv1, a_f, 0, 0, 0);
                a_g = __builtin_amdgcn_mfma_f32_16x16x32_f16(AF[9],  Bv1, a_g, 0, 0, 0);
                a_o = __builtin_amdgcn_mfma_f32_16x16x32_f16(AF[13], Bv1, a_o, 0, 0, 0);
                a_i = __builtin_amdgcn_mfma_f32_16x16x32_f16(AF[2],  Bv2, a_i, 0, 0, 0);
                a_f = __builtin_amdgcn_mfma_f32_16x16x32_f16(AF[6],  Bv2, a_f, 0, 0, 0);
                a_g = __builtin_amdgcn_mfma_f32_16x16x32_f16(AF[10], Bv2, a_g, 0, 0, 0);
                a_o = __builtin_amdgcn_mfma_f32_16x16x32_f16(AF[14], Bv2, a_o, 0, 0, 0);
                a_i = __builtin_amdgcn_mfma_f32_16x16x32_f16(AF[3],  Bv3, a_i, 0, 0, 0);
                a_f = __builtin_amdgcn_mfma_f32_16x16x32_f16(AF[7],  Bv3, a_f, 0, 0, 0);
                a_g = __builtin_amdgcn_mfma_f32_16x16x32_f16(AF[11], Bv3, a_g, 0, 0, 0);
                a_o = __builtin_amdgcn_mfma_f32_16x16x32_f16(AF[15], Bv3, a_o, 0, 0, 0);
                __builtin_amdgcn_s_setprio(0);
                #pragma unroll
                for (int r = 0; r < 4; ++r)
                    if (pwok[r]) {
                        f32x4 v = {a_i[r], a_f[r], a_g[r], a_o[r]};
                        *(f32x4*)(lds + pw[r]) = v;
                    }
                asm volatile("s_waitcnt lgkmcnt(0)" ::: "memory");
                __builtin_amdgcn_sched_barrier(0);
                f32x4 v = *(const f32x4*)(lds + prd);
                const bool updt = upd_ok && ((g == 1) || (n <= Td + 1)); // t in range
                if (updt) {
                    float si = sigm2(v[0]);
                    float sf = sigm2(v[1]);
                    float gg = tanh2(v[2]);
                    float go = sigm2(v[3]);
                    float cn = fmaf(sf, ucs, si * gg);
                    ucs = cn;
                    _Float16 hf = (_Float16)(go * tanh_c(cn));
                    *(_Float16*)(lds + wh1 + wb * str1) = hf;
                    if (g == 1) *(_Float16*)(lds + wh2 + wP12) = hf;
                }
                if (head_ok && n >= 3) {
                    // lane el==4 -> mean (col 0), el==5 -> softplus (col 1)
                    float hv = v[0];
                    if (el == 5) hv = (hv > 30.f) ? hv : __logf(1.f + __expf(hv));
                    const int t = n - 3;
                    g_out[((size_t)(b0 + ub) * Td + t) * 2 + (el - 4)] = hv;
                }
            }
        }
        __syncthreads();   // single barrier: wb writes -> next iter's rb reads
    }
}

extern "C" void kernel_launch(void* const* d_in, const int* in_sizes, int n_in,
                              void* d_out, int out_size, void* d_ws, size_t ws_size,
                              hipStream_t stream) {
    const float* input = (const float*)d_in[0];
    const float* timei = (const float*)d_in[1];
    const float* Wih0  = (const float*)d_in[2];
    const float* Whh0  = (const float*)d_in[3];
    const float* bih0  = (const float*)d_in[4];
    const float* bhh0  = (const float*)d_in[5];
    const float* Wih1  = (const float*)d_in[6];
    const float* Whh1  = (const float*)d_in[7];
    const float* bih1  = (const float*)d_in[8];
    const float* bhh1  = (const float*)d_in[9];
    const float* Wih2  = (const float*)d_in[10];
    const float* Whh2  = (const float*)d_in[11];
    const float* bih2  = (const float*)d_in[12];
    const float* bhh2  = (const float*)d_in[13];
    const float* Wlin  = (const float*)d_in[14];
    const float* blin  = (const float*)d_in[15];
    float* out = (float*)d_out;

    lstm3_mfma<<<dim3(NBLK), dim3(NTH), 0, stream>>>(
        input, timei,
        Wih0, Whh0, bih0, bhh0,
        Wih1, Whh1, bih1, bhh1,
        Wih2, Whh2, bih2, bhh2,
        Wlin, blin, out);
}

// Round 18
// 1670.342 us; speedup vs baseline: 11.3258x; 1.0261x over previous
//
#include <hip/hip_runtime.h>
#include <cstddef>
#include <cstdint>

#define Hd 51
#define Td 2048
#define NBb 4       // batches per block
#define NTH 768     // 12 waves: 4xL0, 4xL1, 4xL2 (one of each per SIMD)
#define NBLK 256    // full chip

typedef _Float16 f16x8 __attribute__((ext_vector_type(8)));
typedef _Float16 f16x4 __attribute__((ext_vector_type(4)));
typedef float    f32x4 __attribute__((ext_vector_type(4)));

// LDS map (as R16):
//  buf0/1/2: double-buffered h panels, chunk-transposed (16B chunks @256B)
//  PRE: per-WAVE private preact transpose blocks [g*4+c] of 64 slots x 16B.
//       Written and read by the SAME wave within one interval -> NO barrier;
//       ordering enforced by s_waitcnt lgkmcnt(0) + sched_barrier.
//  XP : whole-sequence x panel, f16, xp[t][slot], slot = f*4+n
// In-loop barrier is RELAXED: lgkmcnt(0) + raw s_barrier (NO vmcnt drain) --
// the only in-loop vmem op is the head global_store, which nothing reads;
// __syncthreads()'s vmcnt(0) made all 12 waves inherit its ~200-400cyc
// completion latency every iteration.
#define RB0   128
#define RB12  256
#define BASE0 0
#define BASE1 4096
#define BASE2 12288
#define PRE   20480
#define XP    32768
#define LDSB  65536

#define LOG2E  1.44269504f
#define LOG2E2 2.88539008f

__device__ __forceinline__ int vaddr(int base, int rowB, int db, int n, int off) {
    return base + db * (16 * rowB) + ((off >> 4) << 8) + (n << 4) + (off & 15);
}

// preact slot: bijective (m4 = elem&15, n) <-> slot; writer==reader wave
__device__ __forceinline__ int pslot(int m4, int n) {
    return ((m4 ^ n) & 15) | (n << 4);
}

__device__ __forceinline__ float fast_rcp(float x) { return __builtin_amdgcn_rcpf(x); }
__device__ __forceinline__ float exp2_fast(float x) {
#if __has_builtin(__builtin_amdgcn_exp2f)
    return __builtin_amdgcn_exp2f(x);
#else
    return exp2f(x);
#endif
}

// preactivations arrive PRE-SCALED: a' = a*log2e (i,f,o) or a*2*log2e (g)
__device__ __forceinline__ float sigm2(float ap)  { return fast_rcp(1.f + exp2_fast(-ap)); }
__device__ __forceinline__ float tanh2(float ap)  { return fmaf(2.f, fast_rcp(1.f + exp2_fast(-ap)), -1.f); }
__device__ __forceinline__ float tanh_c(float x) {   // x in true units
    float e = exp2_fast(-LOG2E2 * fabsf(x));
    float t = (1.f - e) * fast_rcp(1.f + e);
    return copysignf(t, x);
}

// relaxed workgroup barrier: order LDS only (no vmcnt drain)
__device__ __forceinline__ void lds_barrier() {
    asm volatile("s_waitcnt lgkmcnt(0)" ::: "memory");
    __builtin_amdgcn_sched_barrier(0);
    __builtin_amdgcn_s_barrier();
    __builtin_amdgcn_sched_barrier(0);
}

__global__ __launch_bounds__(NTH, 3)
void lstm3_mfma(const float* __restrict__ g_input, const float* __restrict__ g_time,
                const float* __restrict__ Wih0, const float* __restrict__ Whh0,
                const float* __restrict__ bih0, const float* __restrict__ bhh0,
                const float* __restrict__ Wih1, const float* __restrict__ Whh1,
                const float* __restrict__ bih1, const float* __restrict__ bhh1,
                const float* __restrict__ Wih2, const float* __restrict__ Whh2,
                const float* __restrict__ bih2, const float* __restrict__ bhh2,
                const float* __restrict__ Wlin, const float* __restrict__ blin,
                float* __restrict__ g_out)
{
    __shared__ __align__(16) unsigned char lds[LDSB];

    const int tid  = threadIdx.x;
    const int lane = tid & 63;
    const int w    = tid >> 6;       // wave 0..11
    const int g    = w >> 2;         // layer group: 0=L0, 1=L1, 2=L2
    const int c    = w & 3;          // element-chunk (16 gate-elements / tile set)
    const int ncol = lane & 15;      // batch col (B) / A-row-in-tile
    const int kg   = lane >> 4;      // k-group 0..3
    const int b0   = blockIdx.x * NBb;

    // ---- zero LDS (h buffers must be 0) ----
    for (int i = tid * 4; i < LDSB; i += NTH * 4) *(uint32_t*)(lds + i) = 0u;
    __syncthreads();

    // one-slots (bias column of B) in BOTH double buffers; x(t=0)
    if (tid < 32) {
        int db = tid >> 4, n = tid & 15;
        *(unsigned short*)(lds + vaddr(BASE0, RB0,  db, n,  54 * 2)) = 0x3C00; // f16 1.0
        *(unsigned short*)(lds + vaddr(BASE1, RB12, db, n, 112 * 2)) = 0x3C00;
        *(unsigned short*)(lds + vaddr(BASE2, RB12, db, n, 112 * 2)) = 0x3C00;
    } else if (tid >= 64 && tid < 72) {
        int i = tid - 64; int n = i & 3, f = i >> 2;
        const float* src = f ? g_time : g_input;
        float v = src[(size_t)(b0 + n) * Td];
        *(_Float16*)(lds + vaddr(BASE0, RB0, 0, n, (52 + f) * 2)) = (_Float16)v;
    }

    // ---- preload ALL x into XP panel (coalesced float4, one-time) ----
    for (int i = tid; i < 4096; i += NTH) {
        const int f  = i >> 11;
        const int rm = i & 2047;
        const int n  = rm >> 9;
        const int t4 = rm & 511;
        const float* src = f ? g_time : g_input;
        float4 v = *(const float4*)&src[(size_t)(b0 + n) * Td + 4 * t4];
        const int slot = f * 4 + n;
        #pragma unroll
        for (int j = 0; j < 4; ++j)
            *(_Float16*)(lds + XP + ((((4 * t4 + j) << 3) + slot) << 1)) = (_Float16)((&v.x)[j]);
    }

    // ---- load weight A-fragments (f16, log2e-prescaled) ----
    const int er = 16 * c + ncol;
    const bool rvalid = (er < Hd);
    f16x8 AF[16];   // g0: [0..7] = 4 gates x 2 ksteps; g1/g2: [0..15] = 4 gates x 4 ksteps

    if (g == 0) {
        #pragma unroll
        for (int gs = 0; gs < 4; ++gs) {
            const int sr = gs * Hd + er;
            const float S = (gs == 2) ? LOG2E2 : LOG2E;   // g-gate: tanh(a)=2sig(2a)-1
            #pragma unroll
            for (int s = 0; s < 2; ++s)
                #pragma unroll
                for (int e = 0; e < 8; ++e) {
                    const int kk = 32 * s + 8 * kg + e;
                    float v = 0.f;
                    if (rvalid) {
                        if (kk < 51)                   v = Whh0[sr * 51 + kk];
                        else if (kk == 52 || kk == 53) v = Wih0[sr * 2 + (kk - 52)];
                        else if (kk == 54)             v = bih0[sr] + bhh0[sr];
                    }
                    AF[gs * 2 + s][e] = (_Float16)(v * S);
                }
        }
    } else {
        const float* Wih = (g == 1) ? Wih1 : Wih2;   // prev-layer h (k 0..50)
        const float* Whh = (g == 1) ? Whh1 : Whh2;   // own h (k 56..106)
        const float* bihp = (g == 1) ? bih1 : bih2;
        const float* bhhp = (g == 1) ? bhh1 : bhh2;
        #pragma unroll
        for (int gs = 0; gs < 4; ++gs) {
            const int sr = gs * Hd + er;
            const float S = (gs == 2) ? LOG2E2 : LOG2E;
            #pragma unroll
            for (int s = 0; s < 4; ++s)
                #pragma unroll
                for (int e = 0; e < 8; ++e) {
                    const int kk = 32 * s + 8 * kg + e;
                    float v = 0.f;
                    float sc = S;
                    if (rvalid) {
                        if (kk < 51)                   v = Wih[sr * 51 + kk];
                        else if (kk >= 56 && kk < 107) v = Whh[sr * 51 + (kk - 56)];
                        else if (kk == 112)            v = bihp[sr] + bhhp[sr];
                    } else if (g == 2 && gs == 0 && (er == 52 || er == 53)) {
                        const int hr = er - 52;        // head rows: LINEAR, unscaled
                        sc = 1.f;
                        if (kk >= 56 && kk < 107)      v = Wlin[hr * 51 + (kk - 56)];
                        else if (kk == 112)            v = blin[hr];
                    }
                    AF[gs * 4 + s][e] = (_Float16)(v * sc);
                }
        }
    }

    // ---- hoisted addresses ----
    const f32x4 Z = {0.f, 0.f, 0.f, 0.f};
    const int PAR0 = 16 * RB0;    // db stride buf0
    const int PAR12 = 16 * RB12;  // db stride buf1/2
    int rd0a = vaddr(BASE0, RB0, 0, ncol, 16 * kg);
    int rd0b = vaddr(BASE0, RB0, 0, ncol, 64 + 16 * kg);
    int rd12[4];
    {
        const int baseg = (g == 2) ? BASE2 : BASE1;
        #pragma unroll
        for (int s = 0; s < 4; ++s) rd12[s] = vaddr(baseg, RB12, 0, ncol, 64 * s + 16 * kg);
    }
    // preact write addrs (one per C row r); g2 includes head rows 52,53
    const int e0 = 16 * c + 4 * kg;
    const int elim = (g == 2) ? 54 : Hd;
    int pw[4];
    bool pwok[4];
    #pragma unroll
    for (int r = 0; r < 4; ++r) {
        pw[r] = PRE + ((g * 4 + c) << 10) + (pslot(4 * kg + r, ncol & 3) << 4);
        pwok[r] = (ncol < NBb) && (e0 + r < elim);
    }
    // wave-local transposed read: lane holds cell (eg = 16c + el, b = lane>>4)
    const int el = lane & 15;
    const int ub = lane >> 4;            // batch 0..3
    const int eg = 16 * c + el;          // element 0..63 (valid < 51)
    const int prd = PRE + ((g * 4 + c) << 10) + (pslot(el, ub) << 4);
    const bool upd_ok = (eg < Hd);
    const bool head_ok = (g == 2 && c == 3 && (el == 4 || el == 5)); // eg 52,53
    int wh1, wh2 = -1, str1;
    if (g == 0) {
        wh1 = vaddr(BASE0, RB0,  0, ub, 2 * eg);       str1 = PAR0;
        wh2 = vaddr(BASE1, RB12, 0, ub, 2 * eg);
    } else if (g == 1) {
        wh1 = vaddr(BASE1, RB12, 0, ub, 112 + 2 * eg); str1 = PAR12;
        wh2 = vaddr(BASE2, RB12, 0, ub, 2 * eg);
    } else {
        wh1 = vaddr(BASE2, RB12, 0, ub, 112 + 2 * eg); str1 = PAR12;
    }
    float ucs = 0.f;   // this lane's persistent c-state

    // loop-carried B operands: lanes ncol>=NBb stay ZERO forever (masked reads)
    f16x8 zf;
    #pragma unroll
    for (int e = 0; e < 8; ++e) zf[e] = (_Float16)0.f;
    f16x8 B0 = zf, B1 = zf;                        // g0
    f16x8 Bv0 = zf, Bv1 = zf, Bv2 = zf, Bv3 = zf;  // g1/g2

    __syncthreads();

    // layer skew: iter n computes L0@t=n, L1@t=n-1, L2@t=n-2, head@t=n-3
    // SINGLE relaxed barrier per iteration (LDS-only drain).
    for (int n = 0; n <= Td + 2; ++n) {
        const int rb = n & 1, wb = rb ^ 1;
        const int rP0 = rb * PAR0, rP12 = rb * PAR12;
        const int wP12 = wb * PAR12;

        if (g == 0) {
            const bool dopf = (w == 0 && lane < 8 && (n + 1) < Td);
            _Float16 pfh = (_Float16)0.f;
            const int nb = lane & 3, f = lane >> 2;
            if (dopf)
                pfh = *(const _Float16*)(lds + XP + ((((n + 1) << 3) + lane) << 1));
            if (n < Td) {
                if (ncol < NBb) {
                    B0 = *(const f16x8*)(lds + rd0a + rP0);
                    B1 = *(const f16x8*)(lds + rd0b + rP0);
                }
                f32x4 a_i = Z, a_f = Z, a_g = Z, a_o = Z;
                __builtin_amdgcn_s_setprio(1);
                a_i = __builtin_amdgcn_mfma_f32_16x16x32_f16(AF[0], B0, a_i, 0, 0, 0);
                a_i = __builtin_amdgcn_mfma_f32_16x16x32_f16(AF[1], B1, a_i, 0, 0, 0);
                a_f = __builtin_amdgcn_mfma_f32_16x16x32_f16(AF[2], B0, a_f, 0, 0, 0);
                a_f = __builtin_amdgcn_mfma_f32_16x16x32_f16(AF[3], B1, a_f, 0, 0, 0);
                a_g = __builtin_amdgcn_mfma_f32_16x16x32_f16(AF[4], B0, a_g, 0, 0, 0);
                a_g = __builtin_amdgcn_mfma_f32_16x16x32_f16(AF[5], B1, a_g, 0, 0, 0);
                a_o = __builtin_amdgcn_mfma_f32_16x16x32_f16(AF[6], B0, a_o, 0, 0, 0);
                a_o = __builtin_amdgcn_mfma_f32_16x16x32_f16(AF[7], B1, a_o, 0, 0, 0);
                __builtin_amdgcn_s_setprio(0);
                #pragma unroll
                for (int r = 0; r < 4; ++r)
                    if (pwok[r]) {
                        f32x4 v = {a_i[r], a_f[r], a_g[r], a_o[r]};
                        *(f32x4*)(lds + pw[r]) = v;
                    }
                // wave-local: order read after writes, wait DS pipe
                asm volatile("s_waitcnt lgkmcnt(0)" ::: "memory");
                __builtin_amdgcn_sched_barrier(0);
                f32x4 v = *(const f32x4*)(lds + prd);
                if (upd_ok) {           // t = n
                    float si = sigm2(v[0]);
                    float sf = sigm2(v[1]);
                    float gg = tanh2(v[2]);
                    float go = sigm2(v[3]);
                    float cn = fmaf(sf, ucs, si * gg);
                    ucs = cn;
                    _Float16 hf = (_Float16)(go * tanh_c(cn));
                    *(_Float16*)(lds + wh1 + wb * str1) = hf;
                    *(_Float16*)(lds + wh2 + wP12) = hf;
                }
            }
            if (dopf)
                *(_Float16*)(lds + vaddr(BASE0, RB0, wb, nb, (52 + f) * 2)) = pfh;
        } else {
            const bool act = (g == 1) ? (n >= 1 && n <= Td) : (n >= 2);
            if (act) {
                if (ncol < NBb) {
                    Bv0 = *(const f16x8*)(lds + rd12[0] + rP12);
                    Bv1 = *(const f16x8*)(lds + rd12[1] + rP12);
                    Bv2 = *(const f16x8*)(lds + rd12[2] + rP12);
                    Bv3 = *(const f16x8*)(lds + rd12[3] + rP12);
                }
                f32x4 a_i = Z, a_f = Z, a_g = Z, a_o = Z;
                __builtin_amdgcn_s_setprio(1);
                a_i = __builtin_amdgcn_mfma_f32_16x16x32_f16(AF[0],  Bv0, a_i, 0, 0, 0);
                a_f = __builtin_amdgcn_mfma_f32_16x16x32_f16(AF[4],  Bv0, a_f, 0, 0, 0);
                a_g = __builtin_amdgcn_mfma_f32_16x16x32_f16(AF[8],  Bv0, a_g, 0, 0, 0);
                a_o = __builtin_amdgcn_mfma_f32_16x16x32_f16(AF[12], Bv0, a_o, 0, 0, 0);
                a_i = __builtin_amdgcn_mfma_f32_16x16x32_f16(AF[1],  Bv1, a_i, 0, 0, 0);
                a_f = __builtin_amdgcn_mfma_f32_16x16x32_f16(AF[5],  Bv1, a_f, 0, 0, 0);
                a_g = __builtin_amdgcn_mfma_f32_16x16x32_f16(AF[9],  Bv1, a_g, 0, 0, 0);
                a_o = __builtin_amdgcn_mfma_f32_16x16x32_f16(AF[13], Bv1, a_o, 0, 0, 0);
                a_i = __builtin_amdgcn_mfma_f32_16x16x32_f16(AF[2],  Bv2, a_i, 0, 0, 0);
                a_f = __builtin_amdgcn_mfma_f32_16x16x32_f16(AF[6],  Bv2, a_f, 0, 0, 0);
                a_g = __builtin_amdgcn_mfma_f32_16x16x32_f16(AF[10], Bv2, a_g, 0, 0, 0);
                a_o = __builtin_amdgcn_mfma_f32_16x16x32_f16(AF[14], Bv2, a_o, 0, 0, 0);
                a_i = __builtin_amdgcn_mfma_f32_16x16x32_f16(AF[3],  Bv3, a_i, 0, 0, 0);
                a_f = __builtin_amdgcn_mfma_f32_16x16x32_f16(AF[7],  Bv3, a_f, 0, 0, 0);
                a_g = __builtin_amdgcn_mfma_f32_16x16x32_f16(AF[11], Bv3, a_g, 0, 0, 0);
                a_o = __builtin_amdgcn_mfma_f32_16x16x32_f16(AF[15], Bv3, a_o, 0, 0, 0);
                __builtin_amdgcn_s_setprio(0);
                #pragma unroll
                for (int r = 0; r < 4; ++r)
                    if (pwok[r]) {
                        f32x4 v = {a_i[r], a_f[r], a_g[r], a_o[r]};
                        *(f32x4*)(lds + pw[r]) = v;
                    }
                asm volatile("s_waitcnt lgkmcnt(0)" ::: "memory");
                __builtin_amdgcn_sched_barrier(0);
                f32x4 v = *(const f32x4*)(lds + prd);
                const bool updt = upd_ok && ((g == 1) || (n <= Td + 1)); // t in range
                if (updt) {
                    float si = sigm2(v[0]);
                    float sf = sigm2(v[1]);
                    float gg = tanh2(v[2]);
                    float go = sigm2(v[3]);
                    float cn = fmaf(sf, ucs, si * gg);
                    ucs = cn;
                    _Float16 hf = (_Float16)(go * tanh_c(cn));
                    *(_Float16*)(lds + wh1 + wb * str1) = hf;
                    if (g == 1) *(_Float16*)(lds + wh2 + wP12) = hf;
                }
                if (head_ok && n >= 3) {
                    // lane el==4 -> mean (col 0), el==5 -> softplus (col 1)
                    float hv = v[0];
                    if (el == 5) hv = (hv > 30.f) ? hv : __logf(1.f + __expf(hv));
                    const int t = n - 3;
                    g_out[((size_t)(b0 + ub) * Td + t) * 2 + (el - 4)] = hv;
                }
            }
        }
        lds_barrier();   // relaxed: LDS drain only, head store latency hidden
    }
}

extern "C" void kernel_launch(void* const* d_in, const int* in_sizes, int n_in,
                              void* d_out, int out_size, void* d_ws, size_t ws_size,
                              hipStream_t stream) {
    const float* input = (const float*)d_in[0];
    const float* timei = (const float*)d_in[1];
    const float* Wih0  = (const float*)d_in[2];
    const float* Whh0  = (const float*)d_in[3];
    const float* bih0  = (const float*)d_in[4];
    const float* bhh0  = (const float*)d_in[5];
    const float* Wih1  = (const float*)d_in[6];
    const float* Whh1  = (const float*)d_in[7];
    const float* bih1  = (const float*)d_in[8];
    const float* bhh1  = (const float*)d_in[9];
    const float* Wih2  = (const float*)d_in[10];
    const float* Whh2  = (const float*)d_in[11];
    const float* bih2  = (const float*)d_in[12];
    const float* bhh2  = (const float*)d_in[13];
    const float* Wlin  = (const float*)d_in[14];
    const float* blin  = (const float*)d_in[15];
    float* out = (float*)d_out;

    lstm3_mfma<<<dim3(NBLK), dim3(NTH), 0, stream>>>(
        input, timei,
        Wih0, Whh0, bih0, bhh0,
        Wih1, Whh1, bih1, bhh1,
        Wih2, Whh2, bih2, bhh2,
        Wlin, blin, out);
}